// Round 1
// baseline (668.070 us; speedup 1.0000x reference)
//
#include <hip/hip_runtime.h>
#include <cstddef>
#include <cstdint>

#define S_TOK 8192
#define DDIM  2048
#define NEXP  64
#define CAPTY 128
#define KC    64
#define TPB   64                       // tokens per gemm block
#define NBLK  (S_TOK / TPB)            // 128
#define SEC   (S_TOK * NEXP * CAPTY)   // 67108864

// ---------------------------------------------------------------------------
// Kernel 1: fp32 GEMM (x[64 tok] x wg[64 exp]) + softmax + argmax + per-chunk
// rank/hist/partial-gate-sums. 256 threads, 4x4 register tile per thread.
// LDS layouts: xs[k][t] stride 66 (2-way banks), ws[k][e] stride 64
// (b128 reads at 16*e4: 2-way banks -> free).
// ---------------------------------------------------------------------------
__global__ __launch_bounds__(256)
void gate_gemm_kernel(const float* __restrict__ x, const float* __restrict__ wg,
                      float* __restrict__ gate_s, int* __restrict__ expert,
                      int* __restrict__ rank, int* __restrict__ hist,
                      float* __restrict__ partial_g)
{
    __shared__ float xs[KC][TPB + 2];   // [k][t], row stride 66 floats
    __shared__ float ws[KC][NEXP];      // [k][e], row stride 64 floats
    __shared__ float lg[TPB][NEXP + 1]; // logits [t][e]
    __shared__ float smax[TPB];
    __shared__ float srcp[TPB];
    __shared__ int   sexp[TPB];

    const int tid = threadIdx.x;
    const int e4  = tid & 15;           // expert group -> experts 4*e4..4*e4+3
    const int tg  = tid >> 4;           // token group  -> tokens  4*tg..4*tg+3
    const int t_base = blockIdx.x * TPB;

    float acc[4][4];
#pragma unroll
    for (int i = 0; i < 4; ++i)
#pragma unroll
        for (int j = 0; j < 4; ++j) acc[i][j] = 0.0f;

    for (int kc = 0; kc < DDIM; kc += KC) {
        __syncthreads();
        // stage x tile (64 tok x 64 k) and w tile (64 exp x 64 k), transposed to k-major
#pragma unroll
        for (int m = 0; m < 4; ++m) {
            int idx = tid + 256 * m;        // 0..1023
            int t = idx & 63;               // token / expert row
            int c = idx >> 6;               // float4 column 0..15
            float4 v = *(const float4*)(x + (size_t)(t_base + t) * DDIM + kc + c * 4);
            xs[c * 4 + 0][t] = v.x;
            xs[c * 4 + 1][t] = v.y;
            xs[c * 4 + 2][t] = v.z;
            xs[c * 4 + 3][t] = v.w;
            float4 w = *(const float4*)(wg + (size_t)t * DDIM + kc + c * 4);
            ws[c * 4 + 0][t] = w.x;
            ws[c * 4 + 1][t] = w.y;
            ws[c * 4 + 2][t] = w.z;
            ws[c * 4 + 3][t] = w.w;
        }
        __syncthreads();
#pragma unroll 8
        for (int k = 0; k < KC; ++k) {
            float4 wv = *(const float4*)&ws[k][e4 * 4];
            float2 xa = *(const float2*)&xs[k][tg * 4];
            float2 xb = *(const float2*)&xs[k][tg * 4 + 2];
            float xv0 = xa.x, xv1 = xa.y, xv2 = xb.x, xv3 = xb.y;
            acc[0][0] += xv0 * wv.x; acc[0][1] += xv0 * wv.y;
            acc[0][2] += xv0 * wv.z; acc[0][3] += xv0 * wv.w;
            acc[1][0] += xv1 * wv.x; acc[1][1] += xv1 * wv.y;
            acc[1][2] += xv1 * wv.z; acc[1][3] += xv1 * wv.w;
            acc[2][0] += xv2 * wv.x; acc[2][1] += xv2 * wv.y;
            acc[2][2] += xv2 * wv.z; acc[2][3] += xv2 * wv.w;
            acc[3][0] += xv3 * wv.x; acc[3][1] += xv3 * wv.y;
            acc[3][2] += xv3 * wv.z; acc[3][3] += xv3 * wv.w;
        }
    }

    __syncthreads();
#pragma unroll
    for (int i = 0; i < 4; ++i)
#pragma unroll
        for (int j = 0; j < 4; ++j)
            lg[tg * 4 + i][e4 * 4 + j] = acc[i][j];
    __syncthreads();

    // softmax + argmax per token (wave 0)
    if (tid < TPB) {
        int t = tid;
        float m = -1e30f; int am = 0;
        for (int e = 0; e < NEXP; ++e) {
            float v = lg[t][e];
            if (v > m) { m = v; am = e; }   // strict > keeps first max (np.argmax)
        }
        float s = 0.0f;
        for (int e = 0; e < NEXP; ++e) s += __expf(lg[t][e] - m);
        float rcp = 1.0f / s;               // gates1_s = exp(max-max)/s = 1/s
        smax[t] = m; srcp[t] = rcp; sexp[t] = am;
        gate_s[t_base + t] = rcp;
        expert[t_base + t] = am;
    }
    __syncthreads();

    // rank within 64-token chunk (wave 0)
    if (tid < TPB) {
        int t = tid;
        int em = sexp[t];
        int r = 0;
        for (int u = 0; u < t; ++u) r += (sexp[u] == em) ? 1 : 0;
        rank[t_base + t] = r;
    }
    // per-chunk per-expert histogram + gate column sums (wave 1)
    if (tid >= 64 && tid < 64 + NEXP) {
        int e = tid - 64;
        float pg = 0.0f; int cnt = 0;
        for (int t = 0; t < TPB; ++t) {
            pg  += __expf(lg[t][e] - smax[t]) * srcp[t];
            cnt += (sexp[t] == e) ? 1 : 0;
        }
        partial_g[blockIdx.x * NEXP + e] = pg;
        hist[blockIdx.x * NEXP + e]      = cnt;
    }
}

// ---------------------------------------------------------------------------
// Kernel 2: per-expert exclusive scan over 128 chunks + l_aux -> out[0]
// ---------------------------------------------------------------------------
__global__ __launch_bounds__(64)
void scan_kernel(const int* __restrict__ hist, const float* __restrict__ partial_g,
                 int* __restrict__ chunk_base, float* __restrict__ out)
{
    int e = threadIdx.x;   // 0..63, one wave
    int base = 0;
    float sg = 0.0f;
    for (int c = 0; c < NBLK; ++c) {
        chunk_base[c * NEXP + e] = base;
        base += hist[c * NEXP + e];
        sg   += partial_g[c * NEXP + e];
    }
    float v = sg * (float)base;            // sum_gates[e] * count[e]
#pragma unroll
    for (int off = 32; off > 0; off >>= 1) v += __shfl_down(v, off);
    if (e == 0) {
        // l_aux = E/S^2 * sum_e sum_gates[e]*count[e]
        out[0] = v * (64.0f / (8192.0f * 8192.0f));
    }
}

// ---------------------------------------------------------------------------
// Kernel 3: scatter surviving tokens into combine + dispatch
// ---------------------------------------------------------------------------
__global__ __launch_bounds__(256)
void scatter_kernel(const float* __restrict__ gate_s, const int* __restrict__ expert,
                    const int* __restrict__ rank, const int* __restrict__ chunk_base,
                    float* __restrict__ out)
{
    int s = blockIdx.x * 256 + threadIdx.x;
    if (s >= S_TOK) return;
    int e   = expert[s];
    int loc = chunk_base[(s >> 6) * NEXP + e] + rank[s];
    if (loc < CAPTY) {
        size_t idx = 1 + (size_t)s * (NEXP * CAPTY) + (size_t)e * CAPTY + loc;
        out[idx]       = gate_s[s];   // combine1_sec
        out[idx + SEC] = 1.0f;        // dispatch_mask (bool -> 1.0)
    }
}

extern "C" void kernel_launch(void* const* d_in, const int* in_sizes, int n_in,
                              void* d_out, int out_size, void* d_ws, size_t ws_size,
                              hipStream_t stream)
{
    const float* x  = (const float*)d_in[0];
    const float* wg = (const float*)d_in[1];
    float* out = (float*)d_out;
    char* ws = (char*)d_ws;

    float* gate_s    = (float*)(ws + 0);        //  8192 f32
    int*   expert    = (int*)  (ws + 32768);    //  8192 i32
    int*   rank      = (int*)  (ws + 65536);    //  8192 i32
    int*   hist      = (int*)  (ws + 98304);    //  128*64 i32
    int*   chunk_b   = (int*)  (ws + 131072);   //  128*64 i32
    float* partial_g = (float*)(ws + 163840);   //  128*64 f32

    // zero the (mostly sparse) 537 MB output; everything else overwrites after
    hipMemsetAsync(d_out, 0, (size_t)out_size * sizeof(float), stream);

    gate_gemm_kernel<<<NBLK, 256, 0, stream>>>(x, wg, gate_s, expert, rank, hist, partial_g);
    scan_kernel<<<1, 64, 0, stream>>>(hist, partial_g, chunk_b, out);
    scatter_kernel<<<(S_TOK + 255) / 256, 256, 0, stream>>>(gate_s, expert, rank, chunk_b, out);
}

// Round 2
// 630.840 us; speedup vs baseline: 1.0590x; 1.0590x over previous
//
#include <hip/hip_runtime.h>
#include <cstddef>
#include <cstdint>

#define S_TOK 8192
#define DDIM  2048
#define NEXP  64
#define CAPTY 128
#define KC    64
#define TPB   64                       // tokens per gemm block
#define NBLK  (S_TOK / TPB)            // 128
#define SPLITK 8
#define KPER  (DDIM / SPLITK)          // 256
#define SEC   (S_TOK * NEXP * CAPTY)   // 67108864

// ---------------------------------------------------------------------------
// Kernel 0: vectorized zero-fill of the 537 MB output (replaces slow rocclr
// fill path). Grid-stride float4; one thread handles the odd last element.
// ---------------------------------------------------------------------------
__global__ __launch_bounds__(256)
void fill_zero_kernel(float* __restrict__ out)
{
    const size_t n4 = (size_t)SEC / 2;          // 33,554,432 float4s cover [0, 2*SEC)
    float4* out4 = (float4*)out;
    size_t i = (size_t)blockIdx.x * 256 + threadIdx.x;
    const size_t stride = (size_t)gridDim.x * 256;
    float4 z = make_float4(0.f, 0.f, 0.f, 0.f);
    for (size_t idx = i; idx < n4; idx += stride)
        out4[idx] = z;
    if (i == 0) out[(size_t)2 * SEC] = 0.0f;    // element index 134,217,728
}

// ---------------------------------------------------------------------------
// Kernel 1: split-K fp32 GEMM. Block = (token-chunk tc, k-part kp); computes
// 64 tok x 64 exp over K=256, writes partial logits to ws.
// ---------------------------------------------------------------------------
__global__ __launch_bounds__(256)
void gate_gemm_kernel(const float* __restrict__ x, const float* __restrict__ wg,
                      float* __restrict__ part)
{
    __shared__ float xs[KC][TPB + 2];   // [k][t], row stride 66 floats
    __shared__ float ws[KC][NEXP];      // [k][e]

    const int tid = threadIdx.x;
    const int e4  = tid & 15;           // expert group -> experts 4*e4..+3
    const int tg  = tid >> 4;           // token group  -> tokens  4*tg..+3
    const int kp  = blockIdx.x & (SPLITK - 1);
    const int tc  = blockIdx.x >> 3;
    const int t_base = tc * TPB;
    const int k_base = kp * KPER;

    float acc[4][4];
#pragma unroll
    for (int i = 0; i < 4; ++i)
#pragma unroll
        for (int j = 0; j < 4; ++j) acc[i][j] = 0.0f;

    for (int kc0 = 0; kc0 < KPER; kc0 += KC) {
        const int kc = k_base + kc0;
        __syncthreads();
#pragma unroll
        for (int m = 0; m < 4; ++m) {
            int idx = tid + 256 * m;        // 0..1023
            int t = idx & 63;
            int c = idx >> 6;               // float4 column 0..15
            float4 v = *(const float4*)(x + (size_t)(t_base + t) * DDIM + kc + c * 4);
            xs[c * 4 + 0][t] = v.x;
            xs[c * 4 + 1][t] = v.y;
            xs[c * 4 + 2][t] = v.z;
            xs[c * 4 + 3][t] = v.w;
            float4 w = *(const float4*)(wg + (size_t)t * DDIM + kc + c * 4);
            ws[c * 4 + 0][t] = w.x;
            ws[c * 4 + 1][t] = w.y;
            ws[c * 4 + 2][t] = w.z;
            ws[c * 4 + 3][t] = w.w;
        }
        __syncthreads();
#pragma unroll 8
        for (int k = 0; k < KC; ++k) {
            float4 wv = *(const float4*)&ws[k][e4 * 4];
            float2 xa = *(const float2*)&xs[k][tg * 4];
            float2 xb = *(const float2*)&xs[k][tg * 4 + 2];
            float xv0 = xa.x, xv1 = xa.y, xv2 = xb.x, xv3 = xb.y;
            acc[0][0] += xv0 * wv.x; acc[0][1] += xv0 * wv.y;
            acc[0][2] += xv0 * wv.z; acc[0][3] += xv0 * wv.w;
            acc[1][0] += xv1 * wv.x; acc[1][1] += xv1 * wv.y;
            acc[1][2] += xv1 * wv.z; acc[1][3] += xv1 * wv.w;
            acc[2][0] += xv2 * wv.x; acc[2][1] += xv2 * wv.y;
            acc[2][2] += xv2 * wv.z; acc[2][3] += xv2 * wv.w;
            acc[3][0] += xv3 * wv.x; acc[3][1] += xv3 * wv.y;
            acc[3][2] += xv3 * wv.z; acc[3][3] += xv3 * wv.w;
        }
    }

#pragma unroll
    for (int i = 0; i < 4; ++i) {
        float4 v = make_float4(acc[i][0], acc[i][1], acc[i][2], acc[i][3]);
        *(float4*)(part + ((size_t)kp * S_TOK + t_base + tg * 4 + i) * NEXP + e4 * 4) = v;
    }
}

// ---------------------------------------------------------------------------
// Kernel 2: reduce split-K partials + softmax + argmax + rank/hist/partial_g
// per 64-token chunk. 128 blocks x 64 threads (thread = token in chunk).
// ---------------------------------------------------------------------------
__global__ __launch_bounds__(64)
void softmax_kernel(const float* __restrict__ part,
                    float* __restrict__ gate_s, int* __restrict__ expert,
                    int* __restrict__ rank, int* __restrict__ hist,
                    float* __restrict__ partial_g)
{
    __shared__ float probs[TPB][NEXP + 1];
    __shared__ int   sexp[TPB];

    const int t   = threadIdx.x;        // 0..63
    const int tok = blockIdx.x * TPB + t;

    float lg[NEXP];
#pragma unroll
    for (int e = 0; e < NEXP; e += 4) {
        float4 v = *(const float4*)(part + (size_t)tok * NEXP + e);
        lg[e] = v.x; lg[e + 1] = v.y; lg[e + 2] = v.z; lg[e + 3] = v.w;
    }
#pragma unroll
    for (int kp = 1; kp < SPLITK; ++kp) {
#pragma unroll
        for (int e = 0; e < NEXP; e += 4) {
            float4 v = *(const float4*)(part + ((size_t)kp * S_TOK + tok) * NEXP + e);
            lg[e] += v.x; lg[e + 1] += v.y; lg[e + 2] += v.z; lg[e + 3] += v.w;
        }
    }

    float m = -1e30f; int am = 0;
#pragma unroll
    for (int e = 0; e < NEXP; ++e)
        if (lg[e] > m) { m = lg[e]; am = e; }   // strict > => first max (np.argmax)
    float s = 0.0f;
#pragma unroll
    for (int e = 0; e < NEXP; ++e) { float p = __expf(lg[e] - m); lg[e] = p; s += p; }
    float rcp = 1.0f / s;                       // gates1_s for top-1
#pragma unroll
    for (int e = 0; e < NEXP; ++e) probs[t][e] = lg[e] * rcp;

    sexp[t] = am;
    gate_s[tok] = rcp;
    expert[tok] = am;
    __syncthreads();

    // rank within chunk (token order)
    int r = 0;
    for (int u = 0; u < t; ++u) r += (sexp[u] == am) ? 1 : 0;
    rank[tok] = r;

    // per-chunk per-expert histogram + gate column sums (thread = expert)
    {
        int e = t;
        float pg = 0.0f; int cnt = 0;
        for (int u = 0; u < TPB; ++u) {
            pg  += probs[u][e];
            cnt += (sexp[u] == e) ? 1 : 0;
        }
        partial_g[blockIdx.x * NEXP + e] = pg;
        hist[blockIdx.x * NEXP + e]      = cnt;
    }
}

// ---------------------------------------------------------------------------
// Kernel 3: per-expert exclusive scan over 128 chunks + l_aux -> out[0]
// ---------------------------------------------------------------------------
__global__ __launch_bounds__(64)
void scan_kernel(const int* __restrict__ hist, const float* __restrict__ partial_g,
                 int* __restrict__ chunk_base, float* __restrict__ out)
{
    int e = threadIdx.x;   // 0..63, one wave
    int base = 0;
    float sg = 0.0f;
    for (int c = 0; c < NBLK; ++c) {
        chunk_base[c * NEXP + e] = base;
        base += hist[c * NEXP + e];
        sg   += partial_g[c * NEXP + e];
    }
    float v = sg * (float)base;            // sum_gates[e] * count[e] (pre-drop count)
#pragma unroll
    for (int off = 32; off > 0; off >>= 1) v += __shfl_down(v, off);
    if (e == 0)
        out[0] = v * (64.0f / (8192.0f * 8192.0f));   // l_aux = E/S^2 * sum
}

// ---------------------------------------------------------------------------
// Kernel 4: scatter surviving tokens into combine + dispatch
// ---------------------------------------------------------------------------
__global__ __launch_bounds__(256)
void scatter_kernel(const float* __restrict__ gate_s, const int* __restrict__ expert,
                    const int* __restrict__ rank, const int* __restrict__ chunk_base,
                    float* __restrict__ out)
{
    int s = blockIdx.x * 256 + threadIdx.x;
    if (s >= S_TOK) return;
    int e   = expert[s];
    int loc = chunk_base[(s >> 6) * NEXP + e] + rank[s];
    if (loc < CAPTY) {
        size_t idx = 1 + (size_t)s * (NEXP * CAPTY) + (size_t)e * CAPTY + loc;
        out[idx]       = gate_s[s];   // combine1_sec
        out[idx + SEC] = 1.0f;        // dispatch_mask
    }
}

extern "C" void kernel_launch(void* const* d_in, const int* in_sizes, int n_in,
                              void* d_out, int out_size, void* d_ws, size_t ws_size,
                              hipStream_t stream)
{
    const float* x  = (const float*)d_in[0];
    const float* wg = (const float*)d_in[1];
    float* out = (float*)d_out;
    char* ws = (char*)d_ws;

    // ws layout
    float* part      = (float*)(ws + 0);                       // 8*8192*64 f32 = 16 MB
    size_t off = (size_t)SPLITK * S_TOK * NEXP * sizeof(float);
    float* gate_s    = (float*)(ws + off);          off += 32768;
    int*   expert    = (int*)  (ws + off);          off += 32768;
    int*   rank      = (int*)  (ws + off);          off += 32768;
    int*   hist      = (int*)  (ws + off);          off += 32768;
    int*   chunk_b   = (int*)  (ws + off);          off += 32768;
    float* partial_g = (float*)(ws + off);

    fill_zero_kernel<<<4096, 256, 0, stream>>>(out);
    gate_gemm_kernel<<<NBLK * SPLITK, 256, 0, stream>>>(x, wg, part);
    softmax_kernel<<<NBLK, 64, 0, stream>>>(part, gate_s, expert, rank, hist, partial_g);
    scan_kernel<<<1, 64, 0, stream>>>(hist, partial_g, chunk_b, out);
    scatter_kernel<<<(S_TOK + 255) / 256, 256, 0, stream>>>(gate_s, expert, rank, chunk_b, out);
}